// Round 9
// baseline (1803.859 us; speedup 1.0000x reference)
//
#include <hip/hip_runtime.h>

#define NPTS 80000
#define MPTS 150000
#define NDPTS 10000
#define KOFF 27
#define C3 16
#define CP 259
#define C2 64
#define CM 80
#define CO 96

typedef __attribute__((ext_vector_type(8))) short short8;
typedef __attribute__((ext_vector_type(4))) float f32x4;

__device__ inline short bf16r(float f) {
  union { float f; unsigned u; } x{f};
  unsigned r = (x.u + 0x7fffu + ((x.u >> 16) & 1u)) >> 16;
  return (short)r;
}

// ---------------------------------------------------------------------------
// Weight prep: W[k][ci][n] fp32 -> fragment-ordered bf16
// WbfF[((k*KC+q)*NT+t)*512 + lane*8 + j], B-frag element:
// ci = q*32 + (lane>>4)*8 + j, n = t*16 + (lane&15); ci >= CIN zero-padded.
// ---------------------------------------------------------------------------
__global__ void wfrag_kernel(const float* __restrict__ W, short* __restrict__ WbfF,
                             int CIN, int COUT_, int KC) {
  const int NT = COUT_ / 16;
  int i = blockIdx.x * 256 + threadIdx.x;
  int total = KOFF * KC * NT * 512;
  if (i >= total) return;
  int j = i & 7, lane = (i >> 3) & 63;
  int rest = i >> 9;
  int t = rest % NT; rest /= NT;
  int q = rest % KC;
  int k = rest / KC;
  int ci = q * 32 + (lane >> 4) * 8 + j;
  int n = t * 16 + (lane & 15);
  float v = (ci < CIN) ? W[((size_t)k * CIN + ci) * COUT_ + n] : 0.f;
  WbfF[i] = bf16r(v);
}

// ---------------------------------------------------------------------------
// Wp prep: fp32 [259][64] -> bf16 fragment-ordered [q][t][lane][8], K->288.
// ---------------------------------------------------------------------------
__global__ void wpfrag_kernel(const float* __restrict__ Wp, short* __restrict__ WpF) {
  int i = blockIdx.x * 256 + threadIdx.x;
  if (i >= 9 * 4 * 64 * 8) return;
  int j = i & 7, lane = (i >> 3) & 63, t = (i >> 9) & 3, q = i >> 11;
  int k = q * 32 + (lane >> 4) * 8 + j;
  int n = t * 16 + (lane & 15);
  WpF[i] = (k < CP) ? bf16r(Wp[(size_t)k * C2 + n]) : (short)0;
}

// ---------------------------------------------------------------------------
// Kernel 1: conv3d (16->16) + bn_relu (round-2 version, known good).
// ---------------------------------------------------------------------------
__global__ __launch_bounds__(256) void conv3d_bnrelu_kernel(
    const float* __restrict__ x3d, const int* __restrict__ nbr,
    const float* __restrict__ W3d, const float* __restrict__ g3d,
    const float* __restrict__ b3d, float* __restrict__ y3d,
    float* __restrict__ mix, short* __restrict__ mixbf)
{
  __shared__ float wS[KOFF * C3 * C3];
  __shared__ float fS[16][C3];
  const int tid = threadIdx.x;
  const int base = blockIdx.x * 16;
  for (int e = tid; e < KOFF * C3 * C3; e += 256) wS[e] = W3d[e];
  const int r = tid >> 4, c = tid & 15;
  const int row = base + r;
  float acc = 0.f;
  for (int k = 0; k < KOFF; ++k) {
    int idx = nbr[row * KOFF + k];
    float fv = (idx >= 0) ? x3d[idx * C3 + c] : 0.f;
    __syncthreads();
    fS[r][c] = fv;
    __syncthreads();
    const float* wk = &wS[k * C3 * C3];
    #pragma unroll
    for (int ci = 0; ci < C3; ++ci)
      acc = fmaf(fS[r][ci], wk[ci * C3 + c], acc);
  }
  float v = fmaxf(fmaf(acc, g3d[c], b3d[c]), 0.f);
  y3d[row * C3 + c] = v;
  mix[row * CM + c] = v;
  mixbf[row * CM + c] = bf16r(v);
}

// ---------------------------------------------------------------------------
// Kernel 2: gate/cross fusion (round-4 version).
// ---------------------------------------------------------------------------
__global__ __launch_bounds__(256) void gate_cross_mfma_kernel(
    const float* __restrict__ y3d, const float* __restrict__ f2d,
    const int* __restrict__ nn_idx,
    const float* __restrict__ Wg, const float* __restrict__ bg,
    const float* __restrict__ Wc, const float* __restrict__ bc,
    const short* __restrict__ WpF,
    short* __restrict__ p2dbf, float* __restrict__ cross2d)
{
  constexpr int RS = 296;
  __shared__ short g1S[32 * RS];
  __shared__ short g2S[32 * RS];
  __shared__ float yS[32][C3];
  const int tid = threadIdx.x;
  const int lane = tid & 63;
  const int w = tid >> 6;
  const int lm = lane & 15;
  const int quad = lane >> 4;
  const int base = blockIdx.x * 32;

  for (int e = tid; e < 32 * 32; e += 256) {
    int r = e >> 5, cc = 256 + (e & 31);
    if (cc >= CP) {
      g1S[r * RS + cc] = 0;
      g2S[r * RS + cc] = 0;
    }
  }

  int ix[32];
  #pragma unroll
  for (int r = 0; r < 32; ++r) ix[r] = nn_idx[base + r];

  const int c = tid;
  float f[32];
  #pragma unroll
  for (int r = 0; r < 32; ++r)
    f[r] = (ix[r] >= 0) ? f2d[(size_t)ix[r] * CP + c] : 0.f;

  float ftail = 0.f;
  int tr = 0, tcc = 0;
  if (tid < 96) {
    tr = tid / 3; tcc = tid - tr * 3;
    if (ix[tr] >= 0) ftail = f2d[(size_t)ix[tr] * CP + 256 + tcc];
  }

  for (int e = tid; e < 32 * C3; e += 256)
    ((float*)yS)[e] = y3d[(size_t)base * C3 + e];

  float wg[16], wc[16];
  #pragma unroll
  for (int ci = 0; ci < 16; ++ci) {
    wg[ci] = Wg[ci * CP + c];
    wc[ci] = Wc[ci * CP + c];
  }
  const float bgv = bg[c], bcv = bc[c];

  __syncthreads();

  #pragma unroll
  for (int r = 0; r < 32; ++r) {
    float a1 = bgv, a2 = bcv;
    #pragma unroll
    for (int ci = 0; ci < 16; ++ci) {
      float yv = yS[r][ci];
      a1 = fmaf(yv, wg[ci], a1);
      a2 = fmaf(yv, wc[ci], a2);
    }
    g1S[r * RS + c] = bf16r(fmaxf(a1, 0.f) * f[r]);
    g2S[r * RS + c] = bf16r(fmaxf(a2, 0.f) * f[r]);
  }

  if (tid < 96) {
    const int c2 = 256 + tcc;
    float a1 = bg[c2], a2 = bc[c2];
    #pragma unroll
    for (int ci = 0; ci < 16; ++ci) {
      float yv = yS[tr][ci];
      a1 = fmaf(yv, Wg[ci * CP + c2], a1);
      a2 = fmaf(yv, Wc[ci * CP + c2], a2);
    }
    g1S[tr * RS + c2] = bf16r(fmaxf(a1, 0.f) * ftail);
    g2S[tr * RS + c2] = bf16r(fmaxf(a2, 0.f) * ftail);
  }
  __syncthreads();

  const int gsel = w & 1;
  const int mt = w >> 1;
  const short* gS = gsel ? g2S : g1S;
  f32x4 acc[4];
  #pragma unroll
  for (int t = 0; t < 4; ++t) {
    f32x4 z = {0.f, 0.f, 0.f, 0.f};
    acc[t] = z;
  }
  #pragma unroll
  for (int q = 0; q < 9; ++q) {
    short8 af = *(const short8*)&gS[(mt * 16 + lm) * RS + q * 32 + quad * 8];
    #pragma unroll
    for (int t = 0; t < 4; ++t) {
      short8 bf = *(const short8*)&WpF[(((q * 4 + t) * 64) + lane) * 8];
      acc[t] = __builtin_amdgcn_mfma_f32_16x16x32_bf16(af, bf, acc[t], 0, 0, 0);
    }
  }
  #pragma unroll
  for (int t = 0; t < 4; ++t) {
    const int cc = t * 16 + lm;
    #pragma unroll
    for (int rg = 0; rg < 4; ++rg) {
      const int row = base + mt * 16 + quad * 4 + rg;
      float v = acc[t][rg];
      if (gsel == 0)
        p2dbf[(size_t)row * C2 + cc] = bf16r(v);
      else
        cross2d[(size_t)row * C2 + cc] = v;
    }
  }
}

// ---------------------------------------------------------------------------
// conv_slice: L2-slice-blocked wave-autonomous subm-conv.
//
// r2-r7 evidence: random 160B gathers over a 10-12.8MB table saturate the
// L2-miss/fabric path at ~2.2 TB/s (five designs converged; concurrency
// scaling bought <10%).  Only traffic reduction helps.  The table does NOT
// fit one XCD L2 (4MB) but a quarter does: make S passes over the k-loop,
// each gathering ONLY neighbors with idx in the current slice (exec-masked
// loads -> inactive rows issue no requests; each (row,k) contributes in
// exactly one pass; acc carries across passes).  All blocks work the same
// slice at the same time -> every XCD L2 holds the live slice -> gather
// misses become L2 hits.  Cost: B-loads/MFMAs replicate xS (util was ~10%,
// headroom).  nbr cached in LDS (read HBM once); res/out/nbr use
// nontemporal to avoid polluting slice residency.  No barriers in the k-loop,
// no global_load_lds (r6 trap), same register footprint as r7 (~80 VGPR).
//
// MODE 0: bn_relu -> fp32    MODE 1: bn_relu -> bf16
// MODE 2: relu(bn)+res(stride 64) -> fp32 mix[:,16+c] + bf16 mixbf
// MODE 3: relu(bn+res) -> fp32 + bf16    MODE 4: relu(bn+res) -> bf16
// ---------------------------------------------------------------------------
template <int CIN, int COUT_, int MODE, int MT, int S>
__global__ __launch_bounds__(64, 2) void conv_slice_kernel(
    const short* __restrict__ finbf, const int* __restrict__ nbr, int nrows,
    int inrows,
    const short* __restrict__ WbfF, const float* __restrict__ gamma,
    const float* __restrict__ beta, const float* __restrict__ resf,
    float* __restrict__ outf, short* __restrict__ outbf)
{
  constexpr int KC = (CIN + 31) / 32;   // 32-wide k-chunks per row
  constexpr int DCH = CIN / 8;          // real 16B chunks per row
  constexpr int NT = COUT_ / 16;

  __shared__ int nbrS[MT * 16 * KOFF];

  const int lane = threadIdx.x;
  const int lm = lane & 15;
  const int quad = lane >> 4;
  const int base = blockIdx.x * (MT * 16);

  // ---- nbr -> LDS once (nontemporal; read S times from LDS afterwards) ----
  for (int e = lane; e < MT * 16 * KOFF; e += 64) {
    int r = e / KOFF;
    int row = base + r;
    nbrS[e] = (row < nrows)
        ? __builtin_nontemporal_load(&nbr[(size_t)row * KOFF + (e - r * KOFF)])
        : -1;
  }
  __syncthreads();   // one wave: compiles to cheap s_barrier; pins lgkm order

  f32x4 acc[MT][NT];
  #pragma unroll
  for (int i = 0; i < MT; ++i)
    #pragma unroll
    for (int t = 0; t < NT; ++t) {
      f32x4 z = {0.f, 0.f, 0.f, 0.f};
      acc[i][t] = z;
    }

  const short8 zero8 = {0, 0, 0, 0, 0, 0, 0, 0};

  auto readIdx = [&](int k, int (&id)[MT]) {
    #pragma unroll
    for (int i = 0; i < MT; ++i)
      id[i] = (k < KOFF) ? nbrS[(i * 16 + lm) * KOFF + k] : -1;
  };

  // predicated gather: rows outside [lo,hi) (incl. idx=-1) issue NO requests
  auto loadA = [&](short8 (&pa)[MT][KC], const int (&id)[MT], int lo, int hi) {
    #pragma unroll
    for (int i = 0; i < MT; ++i) {
      #pragma unroll
      for (int q = 0; q < KC; ++q) pa[i][q] = zero8;
      if (id[i] >= lo && id[i] < hi) {
        const short* src = finbf + (size_t)id[i] * CIN;
        #pragma unroll
        for (int q = 0; q < KC; ++q) {
          const int ch = q * 4 + quad;
          if (ch < DCH) pa[i][q] = *(const short8*)(src + ch * 8);
        }
      }
    }
  };

  auto computeK = [&](const short8 (&pa)[MT][KC], int k) {
    const short* wb = WbfF + ((size_t)k * KC * NT) * 512 + lane * 8;
    #pragma unroll
    for (int q = 0; q < KC; ++q) {
      #pragma unroll
      for (int t = 0; t < NT; ++t) {
        short8 bfr = *(const short8*)(wb + (q * NT + t) * 512);
        #pragma unroll
        for (int i = 0; i < MT; ++i)
          acc[i][t] = __builtin_amdgcn_mfma_f32_16x16x32_bf16(pa[i][q], bfr,
                                                              acc[i][t], 0, 0, 0);
      }
    }
  };

  const int SL = inrows / S;

  for (int p = 0; p < S; ++p) {
    const int lo = p * SL;
    const int hi = (p == S - 1) ? inrows : (lo + SL);

    // depth-3 rotating gather pipeline within the pass (27 = 9*3)
    int idt[MT];
    short8 paA[MT][KC], paB[MT][KC], paC[MT][KC];
    readIdx(0, idt); loadA(paA, idt, lo, hi);
    readIdx(1, idt); loadA(paB, idt, lo, hi);

    for (int kk = 0; kk < KOFF; kk += 3) {
      readIdx(kk + 2, idt); loadA(paC, idt, lo, hi);
      computeK(paA, kk);
      readIdx(kk + 3, idt); loadA(paA, idt, lo, hi);  // k>=27 -> -1 -> no load
      computeK(paB, kk + 1);
      readIdx(kk + 4, idt); loadA(paB, idt, lo, hi);
      computeK(paC, kk + 2);
    }
  }

  // ---- epilogue (nontemporal res reads + out writes) ----
  #pragma unroll
  for (int i = 0; i < MT; ++i) {
    int rbase = base + i * 16 + quad * 4;
    #pragma unroll
    for (int t = 0; t < NT; ++t) {
      int cc = t * 16 + lm;
      float g = gamma[cc], b = beta[cc];
      #pragma unroll
      for (int rg = 0; rg < 4; ++rg) {
        int row = rbase + rg;
        if (row >= nrows) continue;
        float v = acc[i][t][rg];
        if (MODE == 0) {
          __builtin_nontemporal_store(fmaxf(fmaf(v, g, b), 0.f),
                                      &outf[(size_t)row * COUT_ + cc]);
        } else if (MODE == 1) {
          __builtin_nontemporal_store(bf16r(fmaxf(fmaf(v, g, b), 0.f)),
                                      &outbf[(size_t)row * COUT_ + cc]);
        } else if (MODE == 2) {
          float r0 = __builtin_nontemporal_load(&resf[(size_t)row * C2 + cc]);
          float o = fmaxf(fmaf(v, g, b), 0.f) + r0;
          __builtin_nontemporal_store(o, &outf[(size_t)row * CM + 16 + cc]);
          __builtin_nontemporal_store(bf16r(o), &outbf[(size_t)row * CM + 16 + cc]);
        } else if (MODE == 3) {
          float r0 = __builtin_nontemporal_load(&resf[(size_t)row * COUT_ + cc]);
          float o = fmaxf(fmaf(v, g, b) + r0, 0.f);
          __builtin_nontemporal_store(o, &outf[(size_t)row * COUT_ + cc]);
          __builtin_nontemporal_store(bf16r(o), &outbf[(size_t)row * COUT_ + cc]);
        } else {
          float r0 = __builtin_nontemporal_load(&resf[(size_t)row * COUT_ + cc]);
          float o = fmaxf(fmaf(v, g, b) + r0, 0.f);
          __builtin_nontemporal_store(bf16r(o), &outbf[(size_t)row * COUT_ + cc]);
        }
      }
    }
  }
}

// ---------------------------------------------------------------------------
extern "C" void kernel_launch(void* const* d_in, const int* in_sizes, int n_in,
                              void* d_out, int out_size, void* d_ws, size_t ws_size,
                              hipStream_t stream) {
  const float* x3d  = (const float*)d_in[0];
  const float* f2d  = (const float*)d_in[1];
  const int*   nn   = (const int*)d_in[2];
  const int*   nbr  = (const int*)d_in[3];
  const int*   nbds = (const int*)d_in[4];
  const float* W3d  = (const float*)d_in[5];
  const float* g3d  = (const float*)d_in[6];
  const float* b3d  = (const float*)d_in[7];
  const float* Wg   = (const float*)d_in[8];
  const float* bg   = (const float*)d_in[9];
  const float* Wc   = (const float*)d_in[10];
  const float* bc   = (const float*)d_in[11];
  const float* Wp   = (const float*)d_in[12];
  const float* W2d  = (const float*)d_in[13];
  const float* g2d  = (const float*)d_in[14];
  const float* b2d  = (const float*)d_in[15];
  const float* Wm1  = (const float*)d_in[16];
  const float* gm1  = (const float*)d_in[17];
  const float* bm1  = (const float*)d_in[18];
  const float* Wm2  = (const float*)d_in[19];
  const float* gm2  = (const float*)d_in[20];
  const float* bm2  = (const float*)d_in[21];
  const float* Wa1  = (const float*)d_in[22];
  const float* ga1  = (const float*)d_in[23];
  const float* ba1  = (const float*)d_in[24];
  const float* Wa2  = (const float*)d_in[25];
  const float* ga2  = (const float*)d_in[26];
  const float* ba2  = (const float*)d_in[27];
  const float* Wds  = (const float*)d_in[28];
  const float* gds  = (const float*)d_in[29];
  const float* bds  = (const float*)d_in[30];

  const size_t N = NPTS;
  float* ws = (float*)d_ws;
  float* y3d     = ws;                    // N*16
  short* p2dbf   = (short*)(ws + N * 16); // N*64 bf16
  float* cross2d = ws + N * 48;           // N*64
  float* mix     = ws + N * 112;          // N*80
  short* mixbf   = (short*)(ws + N * 192);// N*80 bf16
  short* tmp1bf  = (short*)(ws + N * 232);// N*80 bf16
  float* hbuf    = ws + N * 272;          // N*80
  short* hbufbf  = (short*)(ws + N * 352);// N*80 bf16
  short* abufbf  = (short*)ws;            // N*80 bf16 (reuses y3d+p2dbf)
  // fragment-ordered bf16 weights at tail
  short* wtail  = (short*)(ws + N * 392);
  short* WbfF2d = wtail;                   // 27*2*4*512 = 110592
  short* WbfFm1 = WbfF2d + 110592;         // 27*3*5*512 = 207360
  short* WbfFm2 = WbfFm1 + 207360;
  short* WbfFa1 = WbfFm2 + 207360;
  short* WbfFa2 = WbfFa1 + 207360;
  short* WbfFds = WbfFa2 + 207360;         // 27*3*6*512 = 248832
  short* WpF    = WbfFds + 248832;         // 18432

  // ---- weight prep ----
  wfrag_kernel<<<(110592 + 255) / 256, 256, 0, stream>>>(W2d, WbfF2d, 64, 64, 2);
  wfrag_kernel<<<(207360 + 255) / 256, 256, 0, stream>>>(Wm1, WbfFm1, 80, 80, 3);
  wfrag_kernel<<<(207360 + 255) / 256, 256, 0, stream>>>(Wm2, WbfFm2, 80, 80, 3);
  wfrag_kernel<<<(207360 + 255) / 256, 256, 0, stream>>>(Wa1, WbfFa1, 80, 80, 3);
  wfrag_kernel<<<(207360 + 255) / 256, 256, 0, stream>>>(Wa2, WbfFa2, 80, 80, 3);
  wfrag_kernel<<<(248832 + 255) / 256, 256, 0, stream>>>(Wds, WbfFds, 80, 96, 3);
  wpfrag_kernel<<<(9 * 4 * 64 * 8 + 255) / 256, 256, 0, stream>>>(Wp, WpF);

  conv3d_bnrelu_kernel<<<NPTS / 16, 256, 0, stream>>>(x3d, nbr, W3d, g3d, b3d,
                                                      y3d, mix, mixbf);
  gate_cross_mfma_kernel<<<NPTS / 32, 256, 0, stream>>>(y3d, f2d, nn, Wg, bg,
                                                        Wc, bc, WpF, p2dbf,
                                                        cross2d);

  const int gridM2 = (NPTS + 31) / 32;    // 2500 one-wave blocks (MT=2)
  conv_slice_kernel<64, 64, 2, 2, 4><<<gridM2, 64, 0, stream>>>(
      p2dbf, nbr, NPTS, NPTS, WbfF2d, g2d, b2d, cross2d, mix, mixbf);
  conv_slice_kernel<80, 80, 1, 2, 4><<<gridM2, 64, 0, stream>>>(
      mixbf, nbr, NPTS, NPTS, WbfFm1, gm1, bm1, nullptr, nullptr, tmp1bf);
  conv_slice_kernel<80, 80, 3, 2, 4><<<gridM2, 64, 0, stream>>>(
      tmp1bf, nbr, NPTS, NPTS, WbfFm2, gm2, bm2, mix, hbuf, hbufbf);
  conv_slice_kernel<80, 80, 1, 2, 4><<<gridM2, 64, 0, stream>>>(
      hbufbf, nbr, NPTS, NPTS, WbfFa1, ga1, ba1, nullptr, nullptr, tmp1bf);
  conv_slice_kernel<80, 80, 4, 2, 4><<<gridM2, 64, 0, stream>>>(
      tmp1bf, nbr, NPTS, NPTS, WbfFa2, ga2, ba2, hbuf, nullptr, abufbf);

  // small ds conv: gather demand is only ~43MB -> slicing overhead not worth
  // it; S=1 degenerates to the r7 structure (plus LDS-cached nbr).
  const int gridDS = (NDPTS + 15) / 16;   // 625 one-wave blocks (MT=1)
  conv_slice_kernel<80, 96, 0, 1, 1><<<gridDS, 64, 0, stream>>>(
      abufbf, nbds, NDPTS, NPTS, WbfFds, gds, bds, nullptr, (float*)d_out,
      nullptr);
}